// Round 8
// baseline (2534.536 us; speedup 1.0000x reference)
//
#include <hip/hip_runtime.h>
#include <hip/hip_bf16.h>
#include <math.h>

#define VSZ 1056
#define DD 320
#define NH 5
#define HD 64
#define FF 864
#define NL 6
#define NLOOPS 8
#define BB 8
#define SL 2048
#define KK 1638          // int(2048 * 0.8)
#define EPSF 1e-6f

typedef _Float16 f16x8 __attribute__((ext_vector_type(8)));
typedef _Float16 f16x4 __attribute__((ext_vector_type(4)));
typedef float floatx16 __attribute__((ext_vector_type(16)));

__device__ inline void gll16(const void* g, void* l) {
    __builtin_amdgcn_global_load_lds((const __attribute__((address_space(1))) void*)g,
                                     (__attribute__((address_space(3))) void*)l, 16, 0, 0);
}

// pack two f32 -> one int holding 2x f16 (rtz)
__device__ inline int pk16(float a, float b) {
    auto v = __builtin_amdgcn_cvt_pkrtz(a, b);     // __fp16x2
    return *(int*)&v;
}

// ======================= cast fp32 -> fp16 (x4) =======================
__global__ __launch_bounds__(256) void cast4_kernel(const float* __restrict__ s,
        _Float16* __restrict__ d, int n4) {
    int i = blockIdx.x * 256 + threadIdx.x;
    if (i >= n4) return;
    float4 v = ((const float4*)s)[i];
    f16x4 o = { (_Float16)v.x, (_Float16)v.y, (_Float16)v.z, (_Float16)v.w };
    *(f16x4*)(d + (size_t)i * 4) = o;
}

// ======================= embed =======================
__global__ __launch_bounds__(256) void embed_kernel(const int* __restrict__ ids,
        const int* __restrict__ iter, const float* __restrict__ emb,
        const float* __restrict__ iter_emb, float* __restrict__ x) {
    int i = blockIdx.x * 256 + threadIdx.x;          // over B*S*D
    int d = i % DD, bs = i / DD;
    float v = emb[(size_t)ids[bs] * DD + d];
    int it = iter[0];
    if (it < NLOOPS) v += iter_emb[it * DD + d];
    x[i] = v;
}

// ======================= rmsnorm (1 wave per row, D=320 -> 5/lane) =======================
template<typename OT>
__global__ __launch_bounds__(256) void rmsnorm_kernel(const float* __restrict__ x,
        const float* __restrict__ w, OT* __restrict__ out, int nrows) {
    int row = blockIdx.x * 4 + (threadIdx.x >> 6);
    int lane = threadIdx.x & 63;
    if (row >= nrows) return;
    const float* xr = x + (size_t)row * DD;
    float v[5]; float ss = 0.f;
#pragma unroll
    for (int i = 0; i < 5; ++i) { v[i] = xr[lane + i * 64]; ss += v[i] * v[i]; }
#pragma unroll
    for (int o = 32; o > 0; o >>= 1) ss += __shfl_xor(ss, o);
    float r = rsqrtf(ss * (1.f / DD) + EPSF);
    OT* orow = out + (size_t)row * DD;
#pragma unroll
    for (int i = 0; i < 5; ++i) orow[lane + i * 64] = (OT)(w[lane + i * 64] * v[i] * r);
}

// gather selected tokens + rmsnorm -> fp16
__global__ __launch_bounds__(256) void gather_rmsnorm_kernel(const float* __restrict__ x,
        const int* __restrict__ tkidx, const float* __restrict__ w,
        _Float16* __restrict__ out, int nrows) {
    int row = blockIdx.x * 4 + (threadIdx.x >> 6);
    int lane = threadIdx.x & 63;
    if (row >= nrows) return;
    int b = row / KK;
    int t = tkidx[row];
    const float* xr = x + ((size_t)b * SL + t) * DD;
    float v[5]; float ss = 0.f;
#pragma unroll
    for (int i = 0; i < 5; ++i) { v[i] = xr[lane + i * 64]; ss += v[i] * v[i]; }
#pragma unroll
    for (int o = 32; o > 0; o >>= 1) ss += __shfl_xor(ss, o);
    float r = rsqrtf(ss * (1.f / DD) + EPSF);
    _Float16* orow = out + (size_t)row * DD;
#pragma unroll
    for (int i = 0; i < 5; ++i) orow[lane + i * 64] = (_Float16)(w[lane + i * 64] * v[i] * r);
}

// ======================= router: sigmoid(x . rw) =======================
__global__ __launch_bounds__(256) void router_kernel(const float* __restrict__ x,
        const float* __restrict__ rw, float* __restrict__ probs, int nrows) {
    int row = blockIdx.x * 4 + (threadIdx.x >> 6);
    int lane = threadIdx.x & 63;
    if (row >= nrows) return;
    const float* xr = x + (size_t)row * DD;
    float ss = 0.f;
#pragma unroll
    for (int i = 0; i < 5; ++i) ss += xr[lane + i * 64] * rw[lane + i * 64];
#pragma unroll
    for (int o = 32; o > 0; o >>= 1) ss += __shfl_xor(ss, o);
    if (lane == 0) probs[row] = 1.f / (1.f + __expf(-ss));
}

// ======================= top-k: radix select on packed (probbits<<32 | 2047-i) ===========
__global__ __launch_bounds__(1024) void topk_kernel(const float* __restrict__ probs,
        int* __restrict__ tkidx, float* __restrict__ tkprob) {
    __shared__ int hist[256];
    __shared__ int scn[256];
    __shared__ int outc;
    __shared__ int s_digit, s_rem;
    int b = blockIdx.x, tid = threadIdx.x;
    unsigned long long k0, k1;
    {
        unsigned int f0 = __float_as_uint(probs[b * SL + tid]);
        unsigned int f1 = __float_as_uint(probs[b * SL + tid + 1024]);
        k0 = ((unsigned long long)f0 << 32) | (unsigned int)(2047 - tid);
        k1 = ((unsigned long long)f1 << 32) | (unsigned int)(2047 - (tid + 1024));
    }
    if (tid == 0) outc = 0;
    unsigned long long prefix = 0, pmask = 0;
    int target = KK;
    for (int shift = 56; shift >= 0; shift -= 8) {
        if (tid < 256) hist[tid] = 0;
        __syncthreads();
        bool a0 = (k0 & pmask) == prefix;
        bool a1 = (k1 & pmask) == prefix;
        int d0 = (int)((k0 >> shift) & 255);
        int d1 = (int)((k1 >> shift) & 255);
        if (a0) atomicAdd(&hist[d0], 1);
        if (a1) atomicAdd(&hist[d1], 1);
        __syncthreads();
        if (tid < 256) scn[tid] = hist[tid];
        __syncthreads();
#pragma unroll
        for (int st = 1; st < 256; st <<= 1) {       // suffix inclusive scan
            int v = 0;
            if (tid < 256 && tid + st < 256) v = scn[tid + st];
            __syncthreads();
            if (tid < 256) scn[tid] += v;
            __syncthreads();
        }
        if (tid < 256 && hist[tid] > 0) {
            int S = scn[tid];                 // count digit >= tid
            int Sgt = S - hist[tid];          // count digit >  tid
            if (Sgt < target && target <= S) { s_digit = tid; s_rem = target - Sgt; }
        }
        __syncthreads();
        int dsel = s_digit, rem = s_rem;
        bool full = (rem == hist[dsel]);
        if (a0 && (d0 > dsel || (full && d0 == dsel))) {
            int s = atomicAdd(&outc, 1);
            tkidx[b * KK + s] = 2047 - (int)(k0 & 0xffffffffu);
            tkprob[b * KK + s] = __uint_as_float((unsigned int)(k0 >> 32));
        }
        if (a1 && (d1 > dsel || (full && d1 == dsel))) {
            int s = atomicAdd(&outc, 1);
            tkidx[b * KK + s] = 2047 - (int)(k1 & 0xffffffffu);
            tkprob[b * KK + s] = __uint_as_float((unsigned int)(k1 >> 32));
        }
        if (full) break;
        target = rem;
        prefix |= ((unsigned long long)dsel) << shift;
        pmask  |= ((unsigned long long)255) << shift;
        __syncthreads();
    }
}

// ======================= prep: RoPE, Q scaled by log2e/8, V transposed (all fp16) ========
__global__ __launch_bounds__(256) void prep_kernel(const _Float16* __restrict__ qkv,
        _Float16* __restrict__ Qh, _Float16* __restrict__ Kh, _Float16* __restrict__ Vh) {
    __shared__ _Float16 vt[64][72];
    int tid = threadIdx.x;
    int s0 = blockIdx.x * 64, h = blockIdx.y, b = blockIdx.z;
    int bh = b * NH + h;
#pragma unroll
    for (int p = 0; p < 16; ++p) {
        int idx = p * 256 + tid;                 // 64 s x 64 d
        int sl = idx >> 6, d = idx & 63;
        int s = s0 + sl;
        size_t rbase = ((size_t)(b * SL + s) * 3) * (NH * 64) + h * 64;
        float qv = (float)qkv[rbase + d], qp = (float)qkv[rbase + (d ^ 32)];
        float kv = (float)qkv[rbase + NH * 64 + d], kp = (float)qkv[rbase + NH * 64 + (d ^ 32)];
        float vv = (float)qkv[rbase + 2 * NH * 64 + d];
        float freq = exp2f(-(float)(d & 31) * 0.4152410118609203f);   // 10000^(-j/32)
        float ang = (float)s * freq;
        float c = cosf(ang), sn = sinf(ang);
        float qr = (d < 32) ? qv * c - qp * sn : qv * c + qp * sn;
        float kr = (d < 32) ? kv * c - kp * sn : kv * c + kp * sn;
        // 0.125 (1/sqrt(64)) * log2(e): scores land in log2 domain -> exp2 softmax
        Qh[((size_t)bh * SL + s) * 64 + d] = (_Float16)(qr * 0.18033688011112042f);
        Kh[((size_t)bh * SL + s) * 64 + d] = (_Float16)kr;
        vt[sl][d] = (_Float16)vv;
    }
    __syncthreads();
#pragma unroll
    for (int p = 0; p < 16; ++p) {
        int idx = p * 256 + tid;                 // 64 d x 64 s
        int d = idx >> 6, sl = idx & 63;
        Vh[((size_t)bh * 64 + d) * SL + s0 + sl] = vt[sl][d];
    }
}

// ===== attention partial: split-K flash, 1 wave per block, uniform chunks of <=8 tiles ===
// q-tile jq (32 q), chunk c covers 64-key tiles [8c, min(8c+8, jq/2+1)).
// Partials: pml[slot][0..31]=m, [32..63]=l (fp32); pO[slot][q*64+d] fp16 (unnormalized O).
// nchunks(jq) = (jq>>4)+1; slotbase(jq) = jq + 8g(g-1) + (jq&15)g, g=jq>>4.
__global__ __launch_bounds__(64) void attn_part(const _Float16* __restrict__ Qh,
        const _Float16* __restrict__ Kh, const _Float16* __restrict__ Vh,
        float* __restrict__ pml, _Float16* __restrict__ pO) {
    int lane = threadIdx.x;
    int l31 = lane & 31, h5 = lane >> 5;
    int jq = blockIdx.x >> 2, c = blockIdx.x & 3;
    int g = jq >> 4;
    if (c > g) return;                           // nchunks = g+1
    int h = blockIdx.y, b = blockIdx.z;
    int bh = b * NH + h;
    int dt = jq >> 1;                            // diagonal 64-key tile
    int t0c = c * 8;
    int tend = t0c + 8 < dt + 1 ? t0c + 8 : dt + 1;
    int myq = jq * 32 + l31;

    f16x8 qf[4];
    const _Float16* qrow = Qh + ((size_t)bh * SL + myq) * 64;
#pragma unroll
    for (int kd = 0; kd < 4; ++kd)
        qf[kd] = *(const f16x8*)(qrow + kd * 16 + h5 * 8);

    const _Float16* Kb = Kh + ((size_t)bh * SL + l31) * 64 + h5 * 8;
    const _Float16* Vb0 = Vh + ((size_t)bh * 64 + l31) * SL + h5 * 8;
    const _Float16* Vb1 = Vb0 + (size_t)32 * SL;

    floatx16 O0, O1;
#pragma unroll
    for (int r = 0; r < 16; ++r) { O0[r] = 0.f; O1[r] = 0.f; }
    float m = -INFINITY, l = 0.f;

    for (int t = t0c; t < tend; ++t) {
        int t0 = t * 64;
        floatx16 S0, S1;
#pragma unroll
        for (int r = 0; r < 16; ++r) { S0[r] = 0.f; S1[r] = 0.f; }
#pragma unroll
        for (int kd = 0; kd < 4; ++kd) {
            f16x8 a0 = *(const f16x8*)(Kb + (size_t)t0 * 64 + kd * 16);
            f16x8 a1 = *(const f16x8*)(Kb + (size_t)(t0 + 32) * 64 + kd * 16);
            S0 = __builtin_amdgcn_mfma_f32_32x32x16_f16(a0, qf[kd], S0, 0, 0, 0);
            S1 = __builtin_amdgcn_mfma_f32_32x32x16_f16(a1, qf[kd], S1, 0, 0, 0);
        }
        if (t == dt) {                            // diagonal: causal mask
#pragma unroll
            for (int r = 0; r < 16; ++r) {
                int key = t0 + (r & 3) + 8 * (r >> 2) + 4 * h5;
                if (key > myq) S0[r] = -INFINITY;
                if (key + 32 > myq) S1[r] = -INFINITY;
            }
        }
        float tmax = S0[0];
#pragma unroll
        for (int r = 1; r < 16; ++r) tmax = fmaxf(tmax, S0[r]);
#pragma unroll
        for (int r = 0; r < 16; ++r) tmax = fmaxf(tmax, S1[r]);
        tmax = fmaxf(tmax, __shfl_xor(tmax, 32));
        float mnew = fmaxf(m, tmax);
        float alpha = exp2f(m - mnew);            // log2-domain softmax
        float P0[16], P1[16]; float psum = 0.f;
#pragma unroll
        for (int r = 0; r < 16; ++r) { P0[r] = exp2f(S0[r] - mnew); psum += P0[r]; }
#pragma unroll
        for (int r = 0; r < 16; ++r) { P1[r] = exp2f(S1[r] - mnew); psum += P1[r]; }
        psum += __shfl_xor(psum, 32);
        l = l * alpha + psum; m = mnew;
        O0 *= alpha; O1 *= alpha;
        // P (C-layout) -> B-frags via packed-f16 cross-half exchange; V^T frags from global
#pragma unroll
        for (int sub = 0; sub < 2; ++sub) {
            const float* P = sub ? P1 : P0;
#pragma unroll
            for (int kk2 = 0; kk2 < 2; ++kk2) {
                int il0 = pk16(P[kk2 * 8 + 0], P[kk2 * 8 + 1]);
                int il1 = pk16(P[kk2 * 8 + 2], P[kk2 * 8 + 3]);
                int ih0 = pk16(P[kk2 * 8 + 4], P[kk2 * 8 + 5]);
                int ih1 = pk16(P[kk2 * 8 + 6], P[kk2 * 8 + 7]);
                int xl0 = __shfl_xor(il0, 32), xl1 = __shfl_xor(il1, 32);
                int xh0 = __shfl_xor(ih0, 32), xh1 = __shfl_xor(ih1, 32);
                int4 pi;
                pi.x = h5 ? xh0 : il0;
                pi.y = h5 ? xh1 : il1;
                pi.z = h5 ? ih0 : xl0;
                pi.w = h5 ? ih1 : xl1;
                f16x8 pf = *(f16x8*)&pi;
                int ksg = sub * 2 + kk2;
                f16x8 v0 = *(const f16x8*)(Vb0 + t0 + ksg * 16);
                f16x8 v1 = *(const f16x8*)(Vb1 + t0 + ksg * 16);
                O0 = __builtin_amdgcn_mfma_f32_32x32x16_f16(v0, pf, O0, 0, 0, 0);
                O1 = __builtin_amdgcn_mfma_f32_32x32x16_f16(v1, pf, O1, 0, 0, 0);
            }
        }
    }

    int slot = bh * 160 + jq + 8 * g * (g - 1) + (jq & 15) * g + c;
    pml[slot * 64 + h5 * 32 + l31] = h5 ? l : m;
    _Float16* po = pO + (size_t)slot * 2048 + l31 * 64;
#pragma unroll
    for (int r = 0; r < 16; r += 2) {
        int dl = (r & 3) + 8 * (r >> 2) + 4 * h5;
        *(int*)(po + dl)      = pk16(O0[r], O0[r + 1]);
        *(int*)(po + dl + 32) = pk16(O1[r], O1[r + 1]);
    }
}

// ===== attention combine: merge <=4 chunk partials per q-tile, write attn_out ===========
__global__ __launch_bounds__(64) void attn_comb(const float* __restrict__ pml,
        const _Float16* __restrict__ pO, _Float16* __restrict__ attn_out) {
    int lane = threadIdx.x;
    int l31 = lane & 31, h5 = lane >> 5;
    int jq = blockIdx.x, h = blockIdx.y, b = blockIdx.z;
    int bh = b * NH + h;
    int g = jq >> 4;
    int nch = g + 1;
    int slot0 = bh * 160 + jq + 8 * g * (g - 1) + (jq & 15) * g;
    float mc[4], lc[4];
    float M = -INFINITY;
    for (int c = 0; c < nch; ++c) {
        mc[c] = pml[(slot0 + c) * 64 + l31];
        lc[c] = pml[(slot0 + c) * 64 + 32 + l31];
        M = fmaxf(M, mc[c]);
    }
    float L = 0.f;
    float o0[16], o1[16];
#pragma unroll
    for (int r = 0; r < 16; ++r) { o0[r] = 0.f; o1[r] = 0.f; }
    for (int c = 0; c < nch; ++c) {
        float a = exp2f(mc[c] - M);
        L += lc[c] * a;
        const _Float16* po = pO + (size_t)(slot0 + c) * 2048 + l31 * 64;
#pragma unroll
        for (int r = 0; r < 16; r += 2) {
            int dl = (r & 3) + 8 * (r >> 2) + 4 * h5;
            union { int i; _Float16 hh[2]; } u0, u1;
            u0.i = *(const int*)(po + dl);
            u1.i = *(const int*)(po + dl + 32);
            o0[r]     += a * (float)u0.hh[0];
            o0[r + 1] += a * (float)u0.hh[1];
            o1[r]     += a * (float)u1.hh[0];
            o1[r + 1] += a * (float)u1.hh[1];
        }
    }
    float li = 1.f / L;
    int myq = jq * 32 + l31;
    _Float16* orow = attn_out + (size_t)(b * SL + myq) * DD + h * 64;
#pragma unroll
    for (int r = 0; r < 16; ++r) {
        int dl = (r & 3) + 8 * (r >> 2) + 4 * h5;
        orow[dl]      = (_Float16)(o0[r] * li);
        orow[dl + 32] = (_Float16)(o1[r] * li);
    }
}

// ======================= MFMA GEMM: C[M,N] = A[M,K] @ W[N,K]^T (fp16 in, fp32 acc) ======
// MODE 0: Ch = acc (fp16)   MODE 1: X += acc (fp32)
// MODE 2: X[(b*SL+sidx[m])*N+n] += acc*sprob[m]
template<int MODE>
__global__ __launch_bounds__(256) void gemm_mfma(const _Float16* __restrict__ A,
        const _Float16* __restrict__ W, _Float16* __restrict__ Ch, float* __restrict__ X,
        int M, int N, int K, const int* __restrict__ sidx, const float* __restrict__ sprob) {
    __shared__ __attribute__((aligned(16))) _Float16 As[4096];   // [kc][128 rows][8]
    __shared__ __attribute__((aligned(16))) _Float16 Ws[4096];
    int tid = threadIdx.x;
    int lane = tid & 63;
    int wave = tid >> 6;
    int l31 = lane & 31, h5 = lane >> 5;
    int m0 = blockIdx.y * 128, n0 = blockIdx.x * 128;
    int wm = (wave & 1) * 64, wn = (wave >> 1) * 64;

    int srow = tid & 127;
    int skc = tid >> 7;
    int arow = m0 + srow; if (arow >= M) arow = M - 1;
    int wrow = n0 + srow; if (wrow >= N) wrow = N - 1;
    const _Float16* Ag = A + (size_t)arow * K + skc * 8;
    const _Float16* Wg = W + (size_t)wrow * K + skc * 8;
    _Float16* AsD = As + (size_t)(tid & ~63) * 8;
    _Float16* WsD = Ws + (size_t)(tid & ~63) * 8;

    floatx16 acc[2][2];
#pragma unroll
    for (int i = 0; i < 2; ++i)
#pragma unroll
        for (int j = 0; j < 2; ++j)
#pragma unroll
            for (int r = 0; r < 16; ++r) acc[i][j][r] = 0.f;

    for (int k0 = 0; k0 < K; k0 += 32) {
        __syncthreads();
        gll16(Ag + k0, AsD);
        gll16(Ag + k0 + 16, AsD + 2048);
        gll16(Wg + k0, WsD);
        gll16(Wg + k0 + 16, WsD + 2048);
        __syncthreads();
#pragma unroll
        for (int ks = 0; ks < 2; ++ks) {
            int kc = ks * 2 + h5;
            f16x8 a0 = *(const f16x8*)(As + kc * 1024 + (wm + l31) * 8);
            f16x8 a1 = *(const f16x8*)(As + kc * 1024 + (wm + 32 + l31) * 8);
            f16x8 b0 = *(const f16x8*)(Ws + kc * 1024 + (wn + l31) * 8);
            f16x8 b1 = *(const f16x8*)(Ws + kc * 1024 + (wn + 32 + l31) * 8);
            acc[0][0] = __builtin_amdgcn_mfma_f32_32x32x16_f16(a0, b0, acc[0][0], 0, 0, 0);
            acc[0][1] = __builtin_amdgcn_mfma_f32_32x32x16_f16(a0, b1, acc[0][1], 0, 0, 0);
            acc[1][0] = __builtin_amdgcn_mfma_f32_32x32x16_f16(a1, b0, acc[1][0], 0, 0, 0);
            acc[1][1] = __builtin_amdgcn_mfma_f32_32x32x16_f16(a1, b1, acc[1][1], 0, 0, 0);
        }
    }

#pragma unroll
    for (int ti = 0; ti < 2; ++ti) {
#pragma unroll
        for (int r = 0; r < 16; ++r) {
            int mm = m0 + wm + ti * 32 + (r & 3) + 8 * (r >> 2) + 4 * h5;
            if (mm >= M) continue;
            float scale = 1.f;
            float* xrow = nullptr;
            _Float16* crow = nullptr;
            if (MODE == 2) {
                int b = mm / KK;
                scale = sprob[mm];
                xrow = X + ((size_t)(b * SL + sidx[mm])) * N;
            } else if (MODE == 1) {
                xrow = X + (size_t)mm * N;
            } else {
                crow = Ch + (size_t)mm * N;
            }
#pragma unroll
            for (int tj = 0; tj < 2; ++tj) {
                int nn = n0 + wn + tj * 32 + l31;
                if (nn >= N) continue;
                float v = acc[ti][tj][r];
                if (MODE == 0) crow[nn] = (_Float16)v;
                else if (MODE == 1) xrow[nn] += v;
                else xrow[nn] += v * scale;
            }
        }
    }
}

// ============ fused gate+up GEMM: g1 = silu(A@Wg^T) * (A@Wu^T), fp16 out ============
__global__ __launch_bounds__(256) void gemm_gateup(const _Float16* __restrict__ A,
        const _Float16* __restrict__ Wg, const _Float16* __restrict__ Wu,
        _Float16* __restrict__ Ch, int M, int N, int K) {
    __shared__ __attribute__((aligned(16))) _Float16 As[4096];
    __shared__ __attribute__((aligned(16))) _Float16 Wgs[4096];
    __shared__ __attribute__((aligned(16))) _Float16 Wus[4096];
    int tid = threadIdx.x;
    int lane = tid & 63;
    int wave = tid >> 6;
    int l31 = lane & 31, h5 = lane >> 5;
    int m0 = blockIdx.y * 128, n0 = blockIdx.x * 128;
    int wm = (wave & 1) * 64, wn = (wave >> 1) * 64;

    int srow = tid & 127;
    int skc = tid >> 7;
    int arow = m0 + srow; if (arow >= M) arow = M - 1;
    int wrow = n0 + srow; if (wrow >= N) wrow = N - 1;
    const _Float16* Ag  = A  + (size_t)arow * K + skc * 8;
    const _Float16* Wgg = Wg + (size_t)wrow * K + skc * 8;
    const _Float16* Wug = Wu + (size_t)wrow * K + skc * 8;
    _Float16* AsD  = As  + (size_t)(tid & ~63) * 8;
    _Float16* WgsD = Wgs + (size_t)(tid & ~63) * 8;
    _Float16* WusD = Wus + (size_t)(tid & ~63) * 8;

    floatx16 ag[2][2], au[2][2];
#pragma unroll
    for (int i = 0; i < 2; ++i)
#pragma unroll
        for (int j = 0; j < 2; ++j)
#pragma unroll
            for (int r = 0; r < 16; ++r) { ag[i][j][r] = 0.f; au[i][j][r] = 0.f; }

    for (int k0 = 0; k0 < K; k0 += 32) {
        __syncthreads();
        gll16(Ag + k0, AsD);
        gll16(Ag + k0 + 16, AsD + 2048);
        gll16(Wgg + k0, WgsD);
        gll16(Wgg + k0 + 16, WgsD + 2048);
        gll16(Wug + k0, WusD);
        gll16(Wug + k0 + 16, WusD + 2048);
        __syncthreads();
#pragma unroll
        for (int ks = 0; ks < 2; ++ks) {
            int kc = ks * 2 + h5;
            f16x8 a0 = *(const f16x8*)(As + kc * 1024 + (wm + l31) * 8);
            f16x8 a1 = *(const f16x8*)(As + kc * 1024 + (wm + 32 + l31) * 8);
            f16x8 g0 = *(const f16x8*)(Wgs + kc * 1024 + (wn + l31) * 8);
            f16x8 g1f = *(const f16x8*)(Wgs + kc * 1024 + (wn + 32 + l31) * 8);
            f16x8 u0 = *(const f16x8*)(Wus + kc * 1024 + (wn + l31) * 8);
            f16x8 u1 = *(const f16x8*)(Wus + kc * 1024 + (wn + 32 + l31) * 8);
            ag[0][0] = __builtin_amdgcn_mfma_f32_32x32x16_f16(a0, g0, ag[0][0], 0, 0, 0);
            ag[0][1] = __builtin_amdgcn_mfma_f32_32x32x16_f16(a0, g1f, ag[0][1], 0, 0, 0);
            ag[1][0] = __builtin_amdgcn_mfma_f32_32x32x16_f16(a1, g0, ag[1][0], 0, 0, 0);
            ag[1][1] = __builtin_amdgcn_mfma_f32_32x32x16_f16(a1, g1f, ag[1][1], 0, 0, 0);
            au[0][0] = __builtin_amdgcn_mfma_f32_32x32x16_f16(a0, u0, au[0][0], 0, 0, 0);
            au[0][1] = __builtin_amdgcn_mfma_f32_32x32x16_f16(a0, u1, au[0][1], 0, 0, 0);
            au[1][0] = __builtin_amdgcn_mfma_f32_32x32x16_f16(a1, u0, au[1][0], 0, 0, 0);
            au[1][1] = __builtin_amdgcn_mfma_f32_32x32x16_f16(a1, u1, au[1][1], 0, 0, 0);
        }
    }

#pragma unroll
    for (int ti = 0; ti < 2; ++ti) {
#pragma unroll
        for (int r = 0; r < 16; ++r) {
            int mm = m0 + wm + ti * 32 + (r & 3) + 8 * (r >> 2) + 4 * h5;
            if (mm >= M) continue;
            _Float16* crow = Ch + (size_t)mm * N;
#pragma unroll
            for (int tj = 0; tj < 2; ++tj) {
                int nn = n0 + wn + tj * 32 + l31;
                if (nn >= N) continue;
                float gv = ag[ti][tj][r], uv = au[ti][tj][r];
                crow[nn] = (_Float16)((gv / (1.f + __expf(-gv))) * uv);
            }
        }
    }
}

// ======================= launch =======================
extern "C" void kernel_launch(void* const* d_in, const int* in_sizes, int n_in,
                              void* d_out, int out_size, void* d_ws, size_t ws_size,
                              hipStream_t stream) {
    const int*   ids          = (const int*)d_in[0];
    const int*   iter         = (const int*)d_in[1];
    const float* emb          = (const float*)d_in[2];
    const float* iter_emb     = (const float*)d_in[3];
    const float* attn_norm_w  = (const float*)d_in[4];
    const float* Wqkv         = (const float*)d_in[5];
    const float* wo_w         = (const float*)d_in[6];
    const float* router_w     = (const float*)d_in[7];
    const float* mlp_norm_w   = (const float*)d_in[8];
    const float* gate_w       = (const float*)d_in[9];
    const float* up_w         = (const float*)d_in[10];
    const float* down_w       = (const float*)d_in[11];
    const float* final_norm_w = (const float*)d_in[12];
    float* out = (float*)d_out;

    const size_t XN   = (size_t)BB * SL * DD;        // 5,242,880
    const size_t QKVN = (size_t)BB * SL * 3 * DD;    // 15,728,640
    const size_t HN   = (size_t)BB * NH * SL * 64;   // 5,242,880
    char* ws = (char*)d_ws;
    size_t off = 0;
    float*    x        = (float*)(ws + off);    off += XN * 4;
    _Float16* h        = (_Float16*)(ws + off); off += XN * 2;
    _Float16* attn_out = (_Float16*)(ws + off); off += XN * 2;
    float*    probs    = (float*)(ws + off);    off += (size_t)BB * SL * 4;
    int*      tkidx    = (int*)(ws + off);      off += (size_t)BB * KK * 4;
    float*    tkprob   = (float*)(ws + off);    off += (size_t)BB * KK * 4;
    off = (off + 255) & ~(size_t)255;
    _Float16* qkvh     = (_Float16*)(ws + off); off += QKVN * 2;   // reused: partials, then g1
    _Float16* Qh       = (_Float16*)(ws + off); off += HN * 2;
    _Float16* Kh       = (_Float16*)(ws + off); off += HN * 2;
    _Float16* Vh       = (_Float16*)(ws + off); off += HN * 2;
    _Float16* WqkvH    = (_Float16*)(ws + off);
    _Float16* woH   = WqkvH + (size_t)NL * 3 * DD * DD;
    _Float16* gateH = woH   + (size_t)NL * DD * DD;
    _Float16* upH   = gateH + (size_t)NL * FF * DD;
    _Float16* downH = upH   + (size_t)NL * FF * DD;
    _Float16* g1 = qkvh;
    // attention partials overlay qkvh (dead after prep): 40*160 slots
    float*    pml = (float*)qkvh;                          // 40*160*64*4 = 1.64 MB
    _Float16* pOp = (_Float16*)((char*)qkvh + 40 * 160 * 64 * 4);   // 26.2 MB

    cast4_kernel<<<(NL * 3 * DD * DD / 4 + 255) / 256, 256, 0, stream>>>(Wqkv, WqkvH, NL * 3 * DD * DD / 4);
    cast4_kernel<<<(NL * DD * DD / 4 + 255) / 256, 256, 0, stream>>>(wo_w, woH, NL * DD * DD / 4);
    cast4_kernel<<<(NL * FF * DD / 4 + 255) / 256, 256, 0, stream>>>(gate_w, gateH, NL * FF * DD / 4);
    cast4_kernel<<<(NL * FF * DD / 4 + 255) / 256, 256, 0, stream>>>(up_w, upH, NL * FF * DD / 4);
    cast4_kernel<<<(NL * DD * FF / 4 + 255) / 256, 256, 0, stream>>>(down_w, downH, NL * DD * FF / 4);

    embed_kernel<<<20480, 256, 0, stream>>>(ids, iter, emb, iter_emb, x);

    const int M1 = BB * SL;    // 16384
    const int M2 = BB * KK;    // 13104
    for (int l = 0; l < NL; ++l) {
        rmsnorm_kernel<_Float16><<<4096, 256, 0, stream>>>(x, attn_norm_w + l * DD, h, M1);
        gemm_mfma<0><<<dim3(8, 128), 256, 0, stream>>>(h, WqkvH + (size_t)l * 3 * DD * DD,
                                                       qkvh, nullptr, M1, 3 * DD, DD, nullptr, nullptr);
        prep_kernel<<<dim3(SL / 64, NH, BB), 256, 0, stream>>>(qkvh, Qh, Kh, Vh);
        attn_part<<<dim3(256, NH, BB), 64, 0, stream>>>(Qh, Kh, Vh, pml, pOp);
        attn_comb<<<dim3(64, NH, BB), 64, 0, stream>>>(pml, pOp, attn_out);
        gemm_mfma<1><<<dim3(3, 128), 256, 0, stream>>>(attn_out, woH + (size_t)l * DD * DD,
                                                       nullptr, x, M1, DD, DD, nullptr, nullptr);
        router_kernel<<<4096, 256, 0, stream>>>(x, router_w + l * DD, probs, M1);
        topk_kernel<<<BB, 1024, 0, stream>>>(probs, tkidx, tkprob);
        gather_rmsnorm_kernel<<<3276, 256, 0, stream>>>(x, tkidx, mlp_norm_w + l * DD, h, M2);
        gemm_gateup<<<dim3(7, 103), 256, 0, stream>>>(h, gateH + (size_t)l * FF * DD,
                                                      upH + (size_t)l * FF * DD, g1, M2, FF, DD);
        gemm_mfma<2><<<dim3(3, 103), 256, 0, stream>>>(g1, downH + (size_t)l * DD * FF,
                                                       nullptr, x, M2, DD, FF, tkidx, tkprob);
    }
    rmsnorm_kernel<float><<<4096, 256, 0, stream>>>(x, final_norm_w, out, M1);
}

// Round 9
// 2258.335 us; speedup vs baseline: 1.1223x; 1.1223x over previous
//
#include <hip/hip_runtime.h>
#include <hip/hip_bf16.h>
#include <math.h>

#define VSZ 1056
#define DD 320
#define NH 5
#define HD 64
#define FF 864
#define NL 6
#define NLOOPS 8
#define BB 8
#define SL 2048
#define KK 1638          // int(2048 * 0.8)
#define EPSF 1e-6f

typedef _Float16 f16x8 __attribute__((ext_vector_type(8)));
typedef _Float16 f16x4 __attribute__((ext_vector_type(4)));
typedef float floatx16 __attribute__((ext_vector_type(16)));

__device__ inline void gll16(const void* g, void* l) {
    __builtin_amdgcn_global_load_lds((const __attribute__((address_space(1))) void*)g,
                                     (__attribute__((address_space(3))) void*)l, 16, 0, 0);
}

// pack two f32 -> one int holding 2x f16 (rtz)
__device__ inline int pk16(float a, float b) {
    auto v = __builtin_amdgcn_cvt_pkrtz(a, b);     // __fp16x2
    return *(int*)&v;
}

// ======================= cast fp32 -> fp16 (x4) =======================
__global__ __launch_bounds__(256) void cast4_kernel(const float* __restrict__ s,
        _Float16* __restrict__ d, int n4) {
    int i = blockIdx.x * 256 + threadIdx.x;
    if (i >= n4) return;
    float4 v = ((const float4*)s)[i];
    f16x4 o = { (_Float16)v.x, (_Float16)v.y, (_Float16)v.z, (_Float16)v.w };
    *(f16x4*)(d + (size_t)i * 4) = o;
}

// ======================= embed =======================
__global__ __launch_bounds__(256) void embed_kernel(const int* __restrict__ ids,
        const int* __restrict__ iter, const float* __restrict__ emb,
        const float* __restrict__ iter_emb, float* __restrict__ x) {
    int i = blockIdx.x * 256 + threadIdx.x;          // over B*S*D
    int d = i % DD, bs = i / DD;
    float v = emb[(size_t)ids[bs] * DD + d];
    int it = iter[0];
    if (it < NLOOPS) v += iter_emb[it * DD + d];
    x[i] = v;
}

// ======================= rmsnorm (1 wave per row, D=320 -> 5/lane) =======================
template<typename OT>
__global__ __launch_bounds__(256) void rmsnorm_kernel(const float* __restrict__ x,
        const float* __restrict__ w, OT* __restrict__ out, int nrows) {
    int row = blockIdx.x * 4 + (threadIdx.x >> 6);
    int lane = threadIdx.x & 63;
    if (row >= nrows) return;
    const float* xr = x + (size_t)row * DD;
    float v[5]; float ss = 0.f;
#pragma unroll
    for (int i = 0; i < 5; ++i) { v[i] = xr[lane + i * 64]; ss += v[i] * v[i]; }
#pragma unroll
    for (int o = 32; o > 0; o >>= 1) ss += __shfl_xor(ss, o);
    float r = rsqrtf(ss * (1.f / DD) + EPSF);
    OT* orow = out + (size_t)row * DD;
#pragma unroll
    for (int i = 0; i < 5; ++i) orow[lane + i * 64] = (OT)(w[lane + i * 64] * v[i] * r);
}

// gather selected tokens + rmsnorm -> fp16
__global__ __launch_bounds__(256) void gather_rmsnorm_kernel(const float* __restrict__ x,
        const int* __restrict__ tkidx, const float* __restrict__ w,
        _Float16* __restrict__ out, int nrows) {
    int row = blockIdx.x * 4 + (threadIdx.x >> 6);
    int lane = threadIdx.x & 63;
    if (row >= nrows) return;
    int b = row / KK;
    int t = tkidx[row];
    const float* xr = x + ((size_t)b * SL + t) * DD;
    float v[5]; float ss = 0.f;
#pragma unroll
    for (int i = 0; i < 5; ++i) { v[i] = xr[lane + i * 64]; ss += v[i] * v[i]; }
#pragma unroll
    for (int o = 32; o > 0; o >>= 1) ss += __shfl_xor(ss, o);
    float r = rsqrtf(ss * (1.f / DD) + EPSF);
    _Float16* orow = out + (size_t)row * DD;
#pragma unroll
    for (int i = 0; i < 5; ++i) orow[lane + i * 64] = (_Float16)(w[lane + i * 64] * v[i] * r);
}

// ======================= router: sigmoid(x . rw) =======================
__global__ __launch_bounds__(256) void router_kernel(const float* __restrict__ x,
        const float* __restrict__ rw, float* __restrict__ probs, int nrows) {
    int row = blockIdx.x * 4 + (threadIdx.x >> 6);
    int lane = threadIdx.x & 63;
    if (row >= nrows) return;
    const float* xr = x + (size_t)row * DD;
    float ss = 0.f;
#pragma unroll
    for (int i = 0; i < 5; ++i) ss += xr[lane + i * 64] * rw[lane + i * 64];
#pragma unroll
    for (int o = 32; o > 0; o >>= 1) ss += __shfl_xor(ss, o);
    if (lane == 0) probs[row] = 1.f / (1.f + __expf(-ss));
}

// ======================= top-k: radix select on packed (probbits<<32 | 2047-i) ===========
__global__ __launch_bounds__(1024) void topk_kernel(const float* __restrict__ probs,
        int* __restrict__ tkidx, float* __restrict__ tkprob) {
    __shared__ int hist[256];
    __shared__ int scn[256];
    __shared__ int outc;
    __shared__ int s_digit, s_rem;
    int b = blockIdx.x, tid = threadIdx.x;
    unsigned long long k0, k1;
    {
        unsigned int f0 = __float_as_uint(probs[b * SL + tid]);
        unsigned int f1 = __float_as_uint(probs[b * SL + tid + 1024]);
        k0 = ((unsigned long long)f0 << 32) | (unsigned int)(2047 - tid);
        k1 = ((unsigned long long)f1 << 32) | (unsigned int)(2047 - (tid + 1024));
    }
    if (tid == 0) outc = 0;
    unsigned long long prefix = 0, pmask = 0;
    int target = KK;
    for (int shift = 56; shift >= 0; shift -= 8) {
        if (tid < 256) hist[tid] = 0;
        __syncthreads();
        bool a0 = (k0 & pmask) == prefix;
        bool a1 = (k1 & pmask) == prefix;
        int d0 = (int)((k0 >> shift) & 255);
        int d1 = (int)((k1 >> shift) & 255);
        if (a0) atomicAdd(&hist[d0], 1);
        if (a1) atomicAdd(&hist[d1], 1);
        __syncthreads();
        if (tid < 256) scn[tid] = hist[tid];
        __syncthreads();
#pragma unroll
        for (int st = 1; st < 256; st <<= 1) {       // suffix inclusive scan
            int v = 0;
            if (tid < 256 && tid + st < 256) v = scn[tid + st];
            __syncthreads();
            if (tid < 256) scn[tid] += v;
            __syncthreads();
        }
        if (tid < 256 && hist[tid] > 0) {
            int S = scn[tid];                 // count digit >= tid
            int Sgt = S - hist[tid];          // count digit >  tid
            if (Sgt < target && target <= S) { s_digit = tid; s_rem = target - Sgt; }
        }
        __syncthreads();
        int dsel = s_digit, rem = s_rem;
        bool full = (rem == hist[dsel]);
        if (a0 && (d0 > dsel || (full && d0 == dsel))) {
            int s = atomicAdd(&outc, 1);
            tkidx[b * KK + s] = 2047 - (int)(k0 & 0xffffffffu);
            tkprob[b * KK + s] = __uint_as_float((unsigned int)(k0 >> 32));
        }
        if (a1 && (d1 > dsel || (full && d1 == dsel))) {
            int s = atomicAdd(&outc, 1);
            tkidx[b * KK + s] = 2047 - (int)(k1 & 0xffffffffu);
            tkprob[b * KK + s] = __uint_as_float((unsigned int)(k1 >> 32));
        }
        if (full) break;
        target = rem;
        prefix |= ((unsigned long long)dsel) << shift;
        pmask  |= ((unsigned long long)255) << shift;
        __syncthreads();
    }
}

// ======================= prep: RoPE, Q scaled by log2e/8, V transposed (all fp16) ========
__global__ __launch_bounds__(256) void prep_kernel(const _Float16* __restrict__ qkv,
        _Float16* __restrict__ Qh, _Float16* __restrict__ Kh, _Float16* __restrict__ Vh) {
    __shared__ _Float16 vt[64][72];
    int tid = threadIdx.x;
    int s0 = blockIdx.x * 64, h = blockIdx.y, b = blockIdx.z;
    int bh = b * NH + h;
#pragma unroll
    for (int p = 0; p < 16; ++p) {
        int idx = p * 256 + tid;                 // 64 s x 64 d
        int sl = idx >> 6, d = idx & 63;
        int s = s0 + sl;
        size_t rbase = ((size_t)(b * SL + s) * 3) * (NH * 64) + h * 64;
        float qv = (float)qkv[rbase + d], qp = (float)qkv[rbase + (d ^ 32)];
        float kv = (float)qkv[rbase + NH * 64 + d], kp = (float)qkv[rbase + NH * 64 + (d ^ 32)];
        float vv = (float)qkv[rbase + 2 * NH * 64 + d];
        float freq = exp2f(-(float)(d & 31) * 0.4152410118609203f);   // 10000^(-j/32)
        float ang = (float)s * freq;
        float c = cosf(ang), sn = sinf(ang);
        float qr = (d < 32) ? qv * c - qp * sn : qv * c + qp * sn;
        float kr = (d < 32) ? kv * c - kp * sn : kv * c + kp * sn;
        // 0.125 (1/sqrt(64)) * log2(e): scores land in log2 domain -> exp2 softmax
        Qh[((size_t)bh * SL + s) * 64 + d] = (_Float16)(qr * 0.18033688011112042f);
        Kh[((size_t)bh * SL + s) * 64 + d] = (_Float16)kr;
        vt[sl][d] = (_Float16)vv;
    }
    __syncthreads();
#pragma unroll
    for (int p = 0; p < 16; ++p) {
        int idx = p * 256 + tid;                 // 64 d x 64 s
        int d = idx >> 6, sl = idx & 63;
        Vh[((size_t)bh * 64 + d) * SL + s0 + sl] = vt[sl][d];
    }
}

// ===== attention partial: 4-wave blocks, shared LDS K/V tiles (gll16, dbuf, 1 barrier/tile),
// uniform split-K chunks. Block (J, c): waves handle q-tiles jq=4J+w (32 q each); chunk c
// covers 64-key tiles [8c, min(8c+8, 2J+2)). Partials identical to prior scheme:
// pml[slot][0..31]=m,[32..63]=l ; pO[slot] fp16 ; slot = bh*160 + jq + 8g(g-1)+(jq&15)g + c.
__global__ __launch_bounds__(256) void attn_part(const _Float16* __restrict__ Qh,
        const _Float16* __restrict__ Kh, const _Float16* __restrict__ Vh,
        float* __restrict__ pml, _Float16* __restrict__ pO) {
    __shared__ __attribute__((aligned(16))) _Float16 kt[2][4096];  // 64 keys x 8 chunks x 8, XOR swizzle
    __shared__ __attribute__((aligned(16))) _Float16 vt[2][4096];  // 64 d    x 8 chunks x 8, XOR swizzle
    int tid = threadIdx.x;
    int wave = tid >> 6, lane = tid & 63;
    int l31 = lane & 31, h5 = lane >> 5;
    int bx = 63 - (int)blockIdx.x;               // heavy blocks (J=15,c=3) dispatch first
    int J = bx >> 2, c = bx & 3;
    if (8 * c > 2 * J + 1) return;               // inactive chunk (block-uniform)
    int h = blockIdx.y, b = blockIdx.z;
    int bh = b * NH + h;
    int jq = 4 * J + wave;
    int dt = jq >> 1;                            // this wave's diagonal tile
    int tb = c * 8;
    int teB = tb + 8;
    if (teB > 2 * J + 2) teB = 2 * J + 2;        // block-uniform chunk end
    int myq = jq * 32 + l31;

    // q fragments (per wave)
    f16x8 qf[4];
    const _Float16* qrow = Qh + ((size_t)bh * SL + myq) * 64;
#pragma unroll
    for (int kd = 0; kd < 4; ++kd)
        qf[kd] = *(const f16x8*)(qrow + kd * 16 + h5 * 8);

    // gll16 staging: lane-permuted global source -> lane-contiguous LDS = XOR-swizzled tile.
    // LDS chunk i = r*256 + tid ; row = i>>3 ; col = (i&7) ^ (row&7).
    int srowA = tid >> 3;                        // rows 0..31 (r=0); +32 for r=1
    int scol = (tid & 7) ^ (srowA & 7);          // (row+32)&7 == row&7
    const _Float16* Kg0 = Kh + ((size_t)bh * SL + srowA) * 64 + scol * 8;
    const _Float16* Kg1 = Kg0 + (size_t)32 * 64;
    const _Float16* Vg0 = Vh + ((size_t)bh * 64 + srowA) * SL + scol * 8;
    const _Float16* Vg1 = Vg0 + (size_t)32 * SL;
    int ldsw = (tid & ~63) * 8;                  // wave-uniform; HW adds lane*16B

    floatx16 O0, O1;
#pragma unroll
    for (int r = 0; r < 16; ++r) { O0[r] = 0.f; O1[r] = 0.f; }
    float m = -INFINITY, l = 0.f;

    // stage first tile
    {
        int t0 = tb * 64;
        gll16(Kg0 + (size_t)t0 * 64, kt[0] + ldsw);
        gll16(Kg1 + (size_t)t0 * 64, kt[0] + 2048 + ldsw);
        gll16(Vg0 + t0, vt[0] + ldsw);
        gll16(Vg1 + t0, vt[0] + 2048 + ldsw);
    }
    int buf = 0;
    for (int t = tb; t < teB; ++t) {
        __syncthreads();                         // stage(t) complete & visible
        if (t + 1 < teB) {                       // async prefetch next tile into other buffer
            int t0n = (t + 1) * 64;
            gll16(Kg0 + (size_t)t0n * 64, kt[buf ^ 1] + ldsw);
            gll16(Kg1 + (size_t)t0n * 64, kt[buf ^ 1] + 2048 + ldsw);
            gll16(Vg0 + t0n, vt[buf ^ 1] + ldsw);
            gll16(Vg1 + t0n, vt[buf ^ 1] + 2048 + ldsw);
        }
        if (t <= dt) {                           // wave-uniform causal guard
            int t0 = t * 64;
            const _Float16* ktb = kt[buf];
            const _Float16* vtb = vt[buf];
            floatx16 S0, S1;
#pragma unroll
            for (int r = 0; r < 16; ++r) { S0[r] = 0.f; S1[r] = 0.f; }
#pragma unroll
            for (int kd = 0; kd < 4; ++kd) {
                int cix = ((kd * 2 + h5) ^ (l31 & 7)) * 8;
                f16x8 a0 = *(const f16x8*)(ktb + l31 * 64 + cix);
                f16x8 a1 = *(const f16x8*)(ktb + (l31 + 32) * 64 + cix);
                S0 = __builtin_amdgcn_mfma_f32_32x32x16_f16(a0, qf[kd], S0, 0, 0, 0);
                S1 = __builtin_amdgcn_mfma_f32_32x32x16_f16(a1, qf[kd], S1, 0, 0, 0);
            }
            if (t == dt) {                       // diagonal: causal mask
#pragma unroll
                for (int r = 0; r < 16; ++r) {
                    int key = t0 + (r & 3) + 8 * (r >> 2) + 4 * h5;
                    if (key > myq) S0[r] = -INFINITY;
                    if (key + 32 > myq) S1[r] = -INFINITY;
                }
            }
            float tmax = S0[0];
#pragma unroll
            for (int r = 1; r < 16; ++r) tmax = fmaxf(tmax, S0[r]);
#pragma unroll
            for (int r = 0; r < 16; ++r) tmax = fmaxf(tmax, S1[r]);
            tmax = fmaxf(tmax, __shfl_xor(tmax, 32));
            float mnew = fmaxf(m, tmax);
            float alpha = exp2f(m - mnew);       // log2-domain softmax
            float P0[16], P1[16]; float psum = 0.f;
#pragma unroll
            for (int r = 0; r < 16; ++r) { P0[r] = exp2f(S0[r] - mnew); psum += P0[r]; }
#pragma unroll
            for (int r = 0; r < 16; ++r) { P1[r] = exp2f(S1[r] - mnew); psum += P1[r]; }
            psum += __shfl_xor(psum, 32);
            l = l * alpha + psum; m = mnew;
            O0 *= alpha; O1 *= alpha;
            // P (C-layout) -> B-frags via packed-f16 cross-half exchange
#pragma unroll
            for (int sub = 0; sub < 2; ++sub) {
                const float* P = sub ? P1 : P0;
#pragma unroll
                for (int kk2 = 0; kk2 < 2; ++kk2) {
                    int il0 = pk16(P[kk2 * 8 + 0], P[kk2 * 8 + 1]);
                    int il1 = pk16(P[kk2 * 8 + 2], P[kk2 * 8 + 3]);
                    int ih0 = pk16(P[kk2 * 8 + 4], P[kk2 * 8 + 5]);
                    int ih1 = pk16(P[kk2 * 8 + 6], P[kk2 * 8 + 7]);
                    int xl0 = __shfl_xor(il0, 32), xl1 = __shfl_xor(il1, 32);
                    int xh0 = __shfl_xor(ih0, 32), xh1 = __shfl_xor(ih1, 32);
                    int4 pi;
                    pi.x = h5 ? xh0 : il0;
                    pi.y = h5 ? xh1 : il1;
                    pi.z = h5 ? ih0 : xl0;
                    pi.w = h5 ? ih1 : xl1;
                    f16x8 pf = *(f16x8*)&pi;
                    int ksg = sub * 2 + kk2;
                    int vcix = ((ksg * 2 + h5) ^ (l31 & 7)) * 8;
                    f16x8 v0 = *(const f16x8*)(vtb + l31 * 64 + vcix);
                    f16x8 v1 = *(const f16x8*)(vtb + (l31 + 32) * 64 + vcix);
                    O0 = __builtin_amdgcn_mfma_f32_32x32x16_f16(v0, pf, O0, 0, 0, 0);
                    O1 = __builtin_amdgcn_mfma_f32_32x32x16_f16(v1, pf, O1, 0, 0, 0);
                }
            }
        }
        buf ^= 1;
    }

    if (8 * c <= dt) {                           // this wave produced a partial (always true)
        int g = jq >> 4;
        int slot = bh * 160 + jq + 8 * g * (g - 1) + (jq & 15) * g + c;
        pml[slot * 64 + h5 * 32 + l31] = h5 ? l : m;
        _Float16* po = pO + (size_t)slot * 2048 + l31 * 64;
#pragma unroll
        for (int r = 0; r < 16; r += 2) {
            int dl = (r & 3) + 8 * (r >> 2) + 4 * h5;
            *(int*)(po + dl)      = pk16(O0[r], O0[r + 1]);
            *(int*)(po + dl + 32) = pk16(O1[r], O1[r + 1]);
        }
    }
}

// ===== attention combine: merge <=4 chunk partials per q-tile, write attn_out ===========
__global__ __launch_bounds__(64) void attn_comb(const float* __restrict__ pml,
        const _Float16* __restrict__ pO, _Float16* __restrict__ attn_out) {
    int lane = threadIdx.x;
    int l31 = lane & 31, h5 = lane >> 5;
    int jq = blockIdx.x, h = blockIdx.y, b = blockIdx.z;
    int bh = b * NH + h;
    int g = jq >> 4;
    int nch = g + 1;
    int slot0 = bh * 160 + jq + 8 * g * (g - 1) + (jq & 15) * g;
    float mc[4], lc[4];
    float M = -INFINITY;
    for (int c = 0; c < nch; ++c) {
        mc[c] = pml[(slot0 + c) * 64 + l31];
        lc[c] = pml[(slot0 + c) * 64 + 32 + l31];
        M = fmaxf(M, mc[c]);
    }
    float L = 0.f;
    float o0[16], o1[16];
#pragma unroll
    for (int r = 0; r < 16; ++r) { o0[r] = 0.f; o1[r] = 0.f; }
    for (int c = 0; c < nch; ++c) {
        float a = exp2f(mc[c] - M);
        L += lc[c] * a;
        const _Float16* po = pO + (size_t)(slot0 + c) * 2048 + l31 * 64;
#pragma unroll
        for (int r = 0; r < 16; r += 2) {
            int dl = (r & 3) + 8 * (r >> 2) + 4 * h5;
            union { int i; _Float16 hh[2]; } u0, u1;
            u0.i = *(const int*)(po + dl);
            u1.i = *(const int*)(po + dl + 32);
            o0[r]     += a * (float)u0.hh[0];
            o0[r + 1] += a * (float)u0.hh[1];
            o1[r]     += a * (float)u1.hh[0];
            o1[r + 1] += a * (float)u1.hh[1];
        }
    }
    float li = 1.f / L;
    int myq = jq * 32 + l31;
    _Float16* orow = attn_out + (size_t)(b * SL + myq) * DD + h * 64;
#pragma unroll
    for (int r = 0; r < 16; ++r) {
        int dl = (r & 3) + 8 * (r >> 2) + 4 * h5;
        orow[dl]      = (_Float16)(o0[r] * li);
        orow[dl + 32] = (_Float16)(o1[r] * li);
    }
}

// ======================= MFMA GEMM: C[M,N] = A[M,K] @ W[N,K]^T (fp16 in, fp32 acc) ======
// MODE 0: Ch = acc (fp16)   MODE 1: X += acc (fp32)
// MODE 2: X[(b*SL+sidx[m])*N+n] += acc*sprob[m]
template<int MODE>
__global__ __launch_bounds__(256) void gemm_mfma(const _Float16* __restrict__ A,
        const _Float16* __restrict__ W, _Float16* __restrict__ Ch, float* __restrict__ X,
        int M, int N, int K, const int* __restrict__ sidx, const float* __restrict__ sprob) {
    __shared__ __attribute__((aligned(16))) _Float16 As[4096];   // [kc][128 rows][8]
    __shared__ __attribute__((aligned(16))) _Float16 Ws[4096];
    int tid = threadIdx.x;
    int lane = tid & 63;
    int wave = tid >> 6;
    int l31 = lane & 31, h5 = lane >> 5;
    int m0 = blockIdx.y * 128, n0 = blockIdx.x * 128;
    int wm = (wave & 1) * 64, wn = (wave >> 1) * 64;

    int srow = tid & 127;
    int skc = tid >> 7;
    int arow = m0 + srow; if (arow >= M) arow = M - 1;
    int wrow = n0 + srow; if (wrow >= N) wrow = N - 1;
    const _Float16* Ag = A + (size_t)arow * K + skc * 8;
    const _Float16* Wg = W + (size_t)wrow * K + skc * 8;
    _Float16* AsD = As + (size_t)(tid & ~63) * 8;
    _Float16* WsD = Ws + (size_t)(tid & ~63) * 8;

    floatx16 acc[2][2];
#pragma unroll
    for (int i = 0; i < 2; ++i)
#pragma unroll
        for (int j = 0; j < 2; ++j)
#pragma unroll
            for (int r = 0; r < 16; ++r) acc[i][j][r] = 0.f;

    for (int k0 = 0; k0 < K; k0 += 32) {
        __syncthreads();
        gll16(Ag + k0, AsD);
        gll16(Ag + k0 + 16, AsD + 2048);
        gll16(Wg + k0, WsD);
        gll16(Wg + k0 + 16, WsD + 2048);
        __syncthreads();
#pragma unroll
        for (int ks = 0; ks < 2; ++ks) {
            int kc = ks * 2 + h5;
            f16x8 a0 = *(const f16x8*)(As + kc * 1024 + (wm + l31) * 8);
            f16x8 a1 = *(const f16x8*)(As + kc * 1024 + (wm + 32 + l31) * 8);
            f16x8 b0 = *(const f16x8*)(Ws + kc * 1024 + (wn + l31) * 8);
            f16x8 b1 = *(const f16x8*)(Ws + kc * 1024 + (wn + 32 + l31) * 8);
            acc[0][0] = __builtin_amdgcn_mfma_f32_32x32x16_f16(a0, b0, acc[0][0], 0, 0, 0);
            acc[0][1] = __builtin_amdgcn_mfma_f32_32x32x16_f16(a0, b1, acc[0][1], 0, 0, 0);
            acc[1][0] = __builtin_amdgcn_mfma_f32_32x32x16_f16(a1, b0, acc[1][0], 0, 0, 0);
            acc[1][1] = __builtin_amdgcn_mfma_f32_32x32x16_f16(a1, b1, acc[1][1], 0, 0, 0);
        }
    }

#pragma unroll
    for (int ti = 0; ti < 2; ++ti) {
#pragma unroll
        for (int r = 0; r < 16; ++r) {
            int mm = m0 + wm + ti * 32 + (r & 3) + 8 * (r >> 2) + 4 * h5;
            if (mm >= M) continue;
            float scale = 1.f;
            float* xrow = nullptr;
            _Float16* crow = nullptr;
            if (MODE == 2) {
                int b = mm / KK;
                scale = sprob[mm];
                xrow = X + ((size_t)(b * SL + sidx[mm])) * N;
            } else if (MODE == 1) {
                xrow = X + (size_t)mm * N;
            } else {
                crow = Ch + (size_t)mm * N;
            }
#pragma unroll
            for (int tj = 0; tj < 2; ++tj) {
                int nn = n0 + wn + tj * 32 + l31;
                if (nn >= N) continue;
                float v = acc[ti][tj][r];
                if (MODE == 0) crow[nn] = (_Float16)v;
                else if (MODE == 1) xrow[nn] += v;
                else xrow[nn] += v * scale;
            }
        }
    }
}

// ============ fused gate+up GEMM: g1 = silu(A@Wg^T) * (A@Wu^T), fp16 out ============
__global__ __launch_bounds__(256) void gemm_gateup(const _Float16* __restrict__ A,
        const _Float16* __restrict__ Wg, const _Float16* __restrict__ Wu,
        _Float16* __restrict__ Ch, int M, int N, int K) {
    __shared__ __attribute__((aligned(16))) _Float16 As[4096];
    __shared__ __attribute__((aligned(16))) _Float16 Wgs[4096];
    __shared__ __attribute__((aligned(16))) _Float16 Wus[4096];
    int tid = threadIdx.x;
    int lane = tid & 63;
    int wave = tid >> 6;
    int l31 = lane & 31, h5 = lane >> 5;
    int m0 = blockIdx.y * 128, n0 = blockIdx.x * 128;
    int wm = (wave & 1) * 64, wn = (wave >> 1) * 64;

    int srow = tid & 127;
    int skc = tid >> 7;
    int arow = m0 + srow; if (arow >= M) arow = M - 1;
    int wrow = n0 + srow; if (wrow >= N) wrow = N - 1;
    const _Float16* Ag  = A  + (size_t)arow * K + skc * 8;
    const _Float16* Wgg = Wg + (size_t)wrow * K + skc * 8;
    const _Float16* Wug = Wu + (size_t)wrow * K + skc * 8;
    _Float16* AsD  = As  + (size_t)(tid & ~63) * 8;
    _Float16* WgsD = Wgs + (size_t)(tid & ~63) * 8;
    _Float16* WusD = Wus + (size_t)(tid & ~63) * 8;

    floatx16 ag[2][2], au[2][2];
#pragma unroll
    for (int i = 0; i < 2; ++i)
#pragma unroll
        for (int j = 0; j < 2; ++j)
#pragma unroll
            for (int r = 0; r < 16; ++r) { ag[i][j][r] = 0.f; au[i][j][r] = 0.f; }

    for (int k0 = 0; k0 < K; k0 += 32) {
        __syncthreads();
        gll16(Ag + k0, AsD);
        gll16(Ag + k0 + 16, AsD + 2048);
        gll16(Wgg + k0, WgsD);
        gll16(Wgg + k0 + 16, WgsD + 2048);
        gll16(Wug + k0, WusD);
        gll16(Wug + k0 + 16, WusD + 2048);
        __syncthreads();
#pragma unroll
        for (int ks = 0; ks < 2; ++ks) {
            int kc = ks * 2 + h5;
            f16x8 a0 = *(const f16x8*)(As + kc * 1024 + (wm + l31) * 8);
            f16x8 a1 = *(const f16x8*)(As + kc * 1024 + (wm + 32 + l31) * 8);
            f16x8 g0 = *(const f16x8*)(Wgs + kc * 1024 + (wn + l31) * 8);
            f16x8 g1f = *(const f16x8*)(Wgs + kc * 1024 + (wn + 32 + l31) * 8);
            f16x8 u0 = *(const f16x8*)(Wus + kc * 1024 + (wn + l31) * 8);
            f16x8 u1 = *(const f16x8*)(Wus + kc * 1024 + (wn + 32 + l31) * 8);
            ag[0][0] = __builtin_amdgcn_mfma_f32_32x32x16_f16(a0, g0, ag[0][0], 0, 0, 0);
            ag[0][1] = __builtin_amdgcn_mfma_f32_32x32x16_f16(a0, g1f, ag[0][1], 0, 0, 0);
            ag[1][0] = __builtin_amdgcn_mfma_f32_32x32x16_f16(a1, g0, ag[1][0], 0, 0, 0);
            ag[1][1] = __builtin_amdgcn_mfma_f32_32x32x16_f16(a1, g1f, ag[1][1], 0, 0, 0);
            au[0][0] = __builtin_amdgcn_mfma_f32_32x32x16_f16(a0, u0, au[0][0], 0, 0, 0);
            au[0][1] = __builtin_amdgcn_mfma_f32_32x32x16_f16(a0, u1, au[0][1], 0, 0, 0);
            au[1][0] = __builtin_amdgcn_mfma_f32_32x32x16_f16(a1, u0, au[1][0], 0, 0, 0);
            au[1][1] = __builtin_amdgcn_mfma_f32_32x32x16_f16(a1, u1, au[1][1], 0, 0, 0);
        }
    }

#pragma unroll
    for (int ti = 0; ti < 2; ++ti) {
#pragma unroll
        for (int r = 0; r < 16; ++r) {
            int mm = m0 + wm + ti * 32 + (r & 3) + 8 * (r >> 2) + 4 * h5;
            if (mm >= M) continue;
            _Float16* crow = Ch + (size_t)mm * N;
#pragma unroll
            for (int tj = 0; tj < 2; ++tj) {
                int nn = n0 + wn + tj * 32 + l31;
                if (nn >= N) continue;
                float gv = ag[ti][tj][r], uv = au[ti][tj][r];
                crow[nn] = (_Float16)((gv / (1.f + __expf(-gv))) * uv);
            }
        }
    }
}

// ======================= launch =======================
extern "C" void kernel_launch(void* const* d_in, const int* in_sizes, int n_in,
                              void* d_out, int out_size, void* d_ws, size_t ws_size,
                              hipStream_t stream) {
    const int*   ids          = (const int*)d_in[0];
    const int*   iter         = (const int*)d_in[1];
    const float* emb          = (const float*)d_in[2];
    const float* iter_emb     = (const float*)d_in[3];
    const float* attn_norm_w  = (const float*)d_in[4];
    const float* Wqkv         = (const float*)d_in[5];
    const float* wo_w         = (const float*)d_in[6];
    const float* router_w     = (const float*)d_in[7];
    const float* mlp_norm_w   = (const float*)d_in[8];
    const float* gate_w       = (const float*)d_in[9];
    const float* up_w         = (const float*)d_in[10];
    const float* down_w       = (const float*)d_in[11];
    const float* final_norm_w = (const float*)d_in[12];
    float* out = (float*)d_out;

    const size_t XN   = (size_t)BB * SL * DD;        // 5,242,880
    const size_t QKVN = (size_t)BB * SL * 3 * DD;    // 15,728,640
    const size_t HN   = (size_t)BB * NH * SL * 64;   // 5,242,880
    char* ws = (char*)d_ws;
    size_t off = 0;
    float*    x        = (float*)(ws + off);    off += XN * 4;
    _Float16* h        = (_Float16*)(ws + off); off += XN * 2;
    _Float16* attn_out = (_Float16*)(ws + off); off += XN * 2;
    float*    probs    = (float*)(ws + off);    off += (size_t)BB * SL * 4;
    int*      tkidx    = (int*)(ws + off);      off += (size_t)BB * KK * 4;
    float*    tkprob   = (float*)(ws + off);    off += (size_t)BB * KK * 4;
    off = (off + 255) & ~(size_t)255;
    _Float16* qkvh     = (_Float16*)(ws + off); off += QKVN * 2;   // reused: partials, then g1
    _Float16* Qh       = (_Float16*)(ws + off); off += HN * 2;
    _Float16* Kh       = (_Float16*)(ws + off); off += HN * 2;
    _Float16* Vh       = (_Float16*)(ws + off); off += HN * 2;
    _Float16* WqkvH    = (_Float16*)(ws + off);
    _Float16* woH   = WqkvH + (size_t)NL * 3 * DD * DD;
    _Float16* gateH = woH   + (size_t)NL * DD * DD;
    _Float16* upH   = gateH + (size_t)NL * FF * DD;
    _Float16* downH = upH   + (size_t)NL * FF * DD;
    _Float16* g1 = qkvh;
    // attention partials overlay qkvh (dead after prep): 40*160 slots
    float*    pml = (float*)qkvh;                          // 40*160*64*4 = 1.64 MB
    _Float16* pOp = (_Float16*)((char*)qkvh + 40 * 160 * 64 * 4);   // 26.2 MB

    cast4_kernel<<<(NL * 3 * DD * DD / 4 + 255) / 256, 256, 0, stream>>>(Wqkv, WqkvH, NL * 3 * DD * DD / 4);
    cast4_kernel<<<(NL * DD * DD / 4 + 255) / 256, 256, 0, stream>>>(wo_w, woH, NL * DD * DD / 4);
    cast4_kernel<<<(NL * FF * DD / 4 + 255) / 256, 256, 0, stream>>>(gate_w, gateH, NL * FF * DD / 4);
    cast4_kernel<<<(NL * FF * DD / 4 + 255) / 256, 256, 0, stream>>>(up_w, upH, NL * FF * DD / 4);
    cast4_kernel<<<(NL * DD * FF / 4 + 255) / 256, 256, 0, stream>>>(down_w, downH, NL * DD * FF / 4);

    embed_kernel<<<20480, 256, 0, stream>>>(ids, iter, emb, iter_emb, x);

    const int M1 = BB * SL;    // 16384
    const int M2 = BB * KK;    // 13104
    for (int l = 0; l < NL; ++l) {
        rmsnorm_kernel<_Float16><<<4096, 256, 0, stream>>>(x, attn_norm_w + l * DD, h, M1);
        gemm_mfma<0><<<dim3(8, 128), 256, 0, stream>>>(h, WqkvH + (size_t)l * 3 * DD * DD,
                                                       qkvh, nullptr, M1, 3 * DD, DD, nullptr, nullptr);
        prep_kernel<<<dim3(SL / 64, NH, BB), 256, 0, stream>>>(qkvh, Qh, Kh, Vh);
        attn_part<<<dim3(64, NH, BB), 256, 0, stream>>>(Qh, Kh, Vh, pml, pOp);
        attn_comb<<<dim3(64, NH, BB), 64, 0, stream>>>(pml, pOp, attn_out);
        gemm_mfma<1><<<dim3(3, 128), 256, 0, stream>>>(attn_out, woH + (size_t)l * DD * DD,
                                                       nullptr, x, M1, DD, DD, nullptr, nullptr);
        router_kernel<<<4096, 256, 0, stream>>>(x, router_w + l * DD, probs, M1);
        topk_kernel<<<BB, 1024, 0, stream>>>(probs, tkidx, tkprob);
        gather_rmsnorm_kernel<<<3276, 256, 0, stream>>>(x, tkidx, mlp_norm_w + l * DD, h, M2);
        gemm_gateup<<<dim3(7, 103), 256, 0, stream>>>(h, gateH + (size_t)l * FF * DD,
                                                      upH + (size_t)l * FF * DD, g1, M2, FF, DD);
        gemm_mfma<2><<<dim3(3, 103), 256, 0, stream>>>(g1, downH + (size_t)l * DD * FF,
                                                       nullptr, x, M2, DD, FF, tkidx, tkprob);
    }
    rmsnorm_kernel<float><<<4096, 256, 0, stream>>>(x, final_norm_w, out, M1);
}